// Round 7
// baseline (1381.223 us; speedup 1.0000x reference)
//
#include <hip/hip_runtime.h>

#define HDIM 256
#define EPSV 1e-5f
#define SLOPEV 0.01f

typedef __bf16 bf16;
typedef bf16  bf16x8 __attribute__((ext_vector_type(8)));
typedef bf16  bf16x4 __attribute__((ext_vector_type(4)));
typedef float f32x4  __attribute__((ext_vector_type(4)));

#define GLD16(g, l) __builtin_amdgcn_global_load_lds( \
    (const __attribute__((address_space(1))) void*)(g), \
    (__attribute__((address_space(3))) void*)(l), 16, 0, 0)

// ============ MFMA GEMM: 64x128 tile (short-wide), 32x64/wave ============
// out = concat_k(A0..A_{nseg-1}) * Wt^T + bias (+addb residual).
// FUSE_A (r7): BN+leaky applied FRAG-SIDE — A stays on the fast
// global_load_lds path (raw), and the per-K-column affine+leaky runs on the
// A-fragments between ds_read and MFMA, using an LDS coef table staged once
// at prologue. Only the first fuse_nseg segments are transformed (conv: 1,
// W2: 4). r6 post-mortem: reg-staged fusion cost 25us/dispatch from 5
// VMEM/thread/iter + serialization; frag-side is ~70 VALU/wave/iter instead.
// Occupancy: acc 2x4 f32x4 = 32 AGPR, LDS 24KB (+8KB coef when fused),
// launch_bounds(256,5) -> 5 blocks/CU.
template<bool STORE_BF16, bool STATS, bool FUSE_A>
__global__ __launch_bounds__(256, 5)
void gemm_bt_k(const bf16* A0, const bf16* A1, const bf16* A2, const bf16* A3,
               int nseg, int segK,
               const bf16* __restrict__ Wt,
               const float* __restrict__ bias, const bf16* __restrict__ addb,
               void* out0, void* out1, void* out2, void* out3, int ldo,
               int n_store, float* part, int n_stats,
               const float* __restrict__ fcoef, int fuse_nseg, int ncoef)
{
    constexpr int SMEMSZ = FUSE_A ? 32768 : 24576;
    __shared__ char smem[SMEMSZ];

    const int tid = threadIdx.x;
    const int wave = tid >> 6, lane = tid & 63;
    const int quad = lane >> 4, l16 = lane & 15;
    const int waveM = (wave >> 1) * 32, waveN = (wave & 1) * 64;

    // T1: XCD-aware swizzle (guarded on nwg % 8 == 0).
    int bid = blockIdx.y * gridDim.x + blockIdx.x;
    const int nwg = gridDim.x * gridDim.y;
    if ((nwg & 7) == 0) {
        const int cpx = nwg >> 3;
        bid = (bid & 7) * cpx + (bid >> 3);
    }
    const int bx = bid % gridDim.x, by = bid / gridDim.x;
    const int bm = by * 64, bn = bx * 128;
    const int K = nseg * segK;

    const bf16* segs[4] = {A0, A1, A2, A3};
    const int srow = tid >> 2;            // 0..63
    const int skof = (tid & 3) * 8;       // 0,8,16,24 (bf16 elems)

    f32x4 acc[2][4] = {};

    const int T = K >> 5;                 // K-steps of 32

    auto stageA = [&](int s, int kt, int b) {
        const bf16* gA = segs[s] + (size_t)(bm + srow) * segK + kt + skof;
        GLD16(gA, smem + b * 4096 + wave * 1024);
    };
    auto stageB = [&](int s, int kt, int b) {
        const bf16* gB = Wt + (size_t)(bn + srow) * K + s * segK + kt + skof;
        char* lB = smem + 8192 + b * 8192 + wave * 1024;
        GLD16(gB,                  lB);
        GLD16(gB + (size_t)64 * K, lB + 4096);
    };

    // prologue: coef table -> LDS (FUSE only), stage step 0
    if (FUSE_A) {
        float* aT = (float*)(smem + 24576);
        float* bT = aT + 1024;
        for (int i = tid; i < ncoef; i += 256) {
            aT[i] = fcoef[i];
            bT[i] = fcoef[ncoef + i];
        }
    }
    stageA(0, 0, 0);
    stageB(0, 0, 0);
    __syncthreads();

    int s = 0, kt = 0;
    for (int t = 0; t < T; ++t) {
        int s2 = s, kt2 = kt + 32;
        if (kt2 == segK) { s2++; kt2 = 0; }
        if (t + 1 < T) {                   // issue-early prefetch
            stageA(s2, kt2, (t + 1) & 1);
            stageB(s2, kt2, (t + 1) & 1);
        }

        const bf16* pa = (const bf16*)(smem + (t & 1) * 4096)
                         + (waveM + l16) * 32 + quad * 8;
        const bf16* pb = (const bf16*)(smem + 8192 + (t & 1) * 8192)
                         + (waveN + l16) * 32 + quad * 8;
        bf16x8 a0 = *(const bf16x8*)(pa);
        bf16x8 a1 = *(const bf16x8*)(pa + 16 * 32);
        bf16x8 b0 = *(const bf16x8*)(pb);
        bf16x8 b1 = *(const bf16x8*)(pb + 16 * 32);
        bf16x8 b2 = *(const bf16x8*)(pb + 32 * 32);
        bf16x8 b3 = *(const bf16x8*)(pb + 48 * 32);

        if (FUSE_A && s < fuse_nseg) {
            // per-K-column affine + leaky on A-fragments (coefs broadcast
            // across the 16 l16 lanes -> conflict-free LDS reads)
            const float* aT = (const float*)(smem + 24576);
            const float* bT = aT + 1024;
            int kb = s * segK + kt + quad * 8;
            float av[8], dv[8];
            *(float4*)(av)     = *(const float4*)(aT + kb);
            *(float4*)(av + 4) = *(const float4*)(aT + kb + 4);
            *(float4*)(dv)     = *(const float4*)(bT + kb);
            *(float4*)(dv + 4) = *(const float4*)(bT + kb + 4);
#pragma unroll
            for (int u = 0; u < 8; ++u) {
                float f0 = fmaf((float)a0[u], av[u], dv[u]);
                f0 = f0 > 0.f ? f0 : SLOPEV * f0;
                a0[u] = (bf16)f0;
                float f1 = fmaf((float)a1[u], av[u], dv[u]);
                f1 = f1 > 0.f ? f1 : SLOPEV * f1;
                a1[u] = (bf16)f1;
            }
        }

        acc[0][0] = __builtin_amdgcn_mfma_f32_16x16x32_bf16(a0, b0, acc[0][0], 0, 0, 0);
        acc[0][1] = __builtin_amdgcn_mfma_f32_16x16x32_bf16(a0, b1, acc[0][1], 0, 0, 0);
        acc[0][2] = __builtin_amdgcn_mfma_f32_16x16x32_bf16(a0, b2, acc[0][2], 0, 0, 0);
        acc[0][3] = __builtin_amdgcn_mfma_f32_16x16x32_bf16(a0, b3, acc[0][3], 0, 0, 0);
        acc[1][0] = __builtin_amdgcn_mfma_f32_16x16x32_bf16(a1, b0, acc[1][0], 0, 0, 0);
        acc[1][1] = __builtin_amdgcn_mfma_f32_16x16x32_bf16(a1, b1, acc[1][1], 0, 0, 0);
        acc[1][2] = __builtin_amdgcn_mfma_f32_16x16x32_bf16(a1, b2, acc[1][2], 0, 0, 0);
        acc[1][3] = __builtin_amdgcn_mfma_f32_16x16x32_bf16(a1, b3, acc[1][3], 0, 0, 0);

        __syncthreads();
        s = s2; kt = kt2;
    }

    float bv[4];
#pragma unroll
    for (int j = 0; j < 4; ++j)
        bv[j] = bias ? bias[bn + waveN + j * 16 + l16] : 0.f;
#pragma unroll
    for (int i = 0; i < 2; ++i)
#pragma unroll
        for (int j = 0; j < 4; ++j)
#pragma unroll
            for (int r = 0; r < 4; ++r)
                acc[i][j][r] += bv[j];

    void* outs[4] = {out0, out1, out2, out3};

    if (STORE_BF16) {
        // wave-private 32x64 staging tile, row stride 72 bf16 (144B, 16B-mult)
        char* stg = smem + wave * 4608;
        float s8[8] = {}, q8[8] = {};
        const int rsel = lane >> 3, csel = lane & 7;
#pragma unroll
        for (int i = 0; i < 2; ++i)
#pragma unroll
            for (int j = 0; j < 4; ++j)
#pragma unroll
                for (int r = 0; r < 4; ++r)
                    *(bf16*)(stg + ((i * 16 + quad * 4 + r) * 72 + j * 16 + l16) * 2)
                        = (bf16)acc[i][j][r];
        // same-wave DS ops are in-order: reads below see writes above
#pragma unroll
        for (int rr = 0; rr < 4; ++rr) {
            int rl = rsel + rr * 8;
            bf16x8 v = *(const bf16x8*)(stg + (rl * 72 + csel * 8) * 2);
            int rowg = bm + waveM + rl;
            int colg = bn + waveN + csel * 8;
            int cseg = colg >> 8, cloc = colg & 255;
            size_t idx = (size_t)rowg * ldo + cloc;
            float f[8];
#pragma unroll
            for (int u = 0; u < 8; ++u) f[u] = (float)v[u];
            if (addb) {
                bf16x8 o = *(const bf16x8*)(addb + idx);
#pragma unroll
                for (int u = 0; u < 8; ++u) f[u] += (float)o[u];
            }
            bf16x8 w;
#pragma unroll
            for (int u = 0; u < 8; ++u) w[u] = (bf16)f[u];
            if (rowg < n_store) *(bf16x8*)((bf16*)outs[cseg] + idx) = w;
            if (STATS && rowg < n_stats) {
#pragma unroll
                for (int u = 0; u < 8; ++u) { s8[u] += f[u]; q8[u] += f[u] * f[u]; }
            }
        }
        if (STATS) {
            // reduce across rsel (lane bits 3..5)
#pragma unroll
            for (int m = 8; m <= 32; m <<= 1)
#pragma unroll
                for (int u = 0; u < 8; ++u) {
                    s8[u] += __shfl_xor(s8[u], m, 64);
                    q8[u] += __shfl_xor(q8[u], m, 64);
                }
            float* Ls = (float*)(smem + 18432);   // [4][64]
            float* Lq = Ls + 256;                 // [4][64]
            if (rsel == 0) {
#pragma unroll
                for (int u = 0; u < 8; ++u) {
                    Ls[wave * 64 + csel * 8 + u] = s8[u];
                    Lq[wave * 64 + csel * 8 + u] = q8[u];
                }
            }
            __syncthreads();
            if (tid < 128) {
                // cols 0..63: waves 0,2 ; cols 64..127: waves 1,3
                int hi = tid >> 6, c6 = tid & 63;
                float sv = Ls[hi * 64 + c6] + Ls[(hi + 2) * 64 + c6];
                float qv = Lq[hi * 64 + c6] + Lq[(hi + 2) * 64 + c6];
                int Mtot = gridDim.x * 128;
                int colg = bn + tid;
                part[(size_t)by * Mtot + colg] = sv;
                part[(size_t)(gridDim.y + by) * Mtot + colg] = qv;
            }
        }
    } else {
#pragma unroll
        for (int i = 0; i < 2; ++i)
#pragma unroll
            for (int j = 0; j < 4; ++j) {
                int colg = bn + waveN + j * 16 + l16;
                int cseg = colg >> 8, cloc = colg & 255;
#pragma unroll
                for (int r = 0; r < 4; ++r) {
                    int rowg = bm + waveM + i * 16 + quad * 4 + r;
                    if (rowg < n_store)
                        ((float*)outs[cseg])[(size_t)rowg * ldo + cloc] = acc[i][j][r];
                }
            }
    }
}

// ================= finalize: one block per column, tree reduce =================
__global__ __launch_bounds__(256)
void finalize_k(const float* __restrict__ part, int GY, int M,
                const float* __restrict__ g, const float* __restrict__ bb,
                float* __restrict__ coef, float invn)
{
    const int c = blockIdx.x;
    const int t = threadIdx.x;
    float s = 0.f, q = 0.f;
    const float* ps = part + c;
    const float* pq = part + (size_t)GY * M + c;
    for (int i = t; i < GY; i += 256) {
        s += ps[(size_t)i * M];
        q += pq[(size_t)i * M];
    }
#pragma unroll
    for (int m = 1; m <= 32; m <<= 1) {
        s += __shfl_xor(s, m, 64);
        q += __shfl_xor(q, m, 64);
    }
    __shared__ float Ls[4], Lq[4];
    const int w = t >> 6, l = t & 63;
    if (l == 0) { Ls[w] = s; Lq[w] = q; }
    __syncthreads();
    if (t == 0) {
        s = Ls[0] + Ls[1] + Ls[2] + Ls[3];
        q = Lq[0] + Lq[1] + Lq[2] + Lq[3];
        float mean = s * invn;
        float var  = q * invn - mean * mean;
        float a = g[c] * rsqrtf(var + EPSV);
        coef[c]     = a;
        coef[M + c] = bb[c] - mean * a;
    }
}

// ================= transpose+convert =================
__global__ __launch_bounds__(256)
void transpose_cvt_k(const float* __restrict__ src, bf16* __restrict__ dst,
                     int Kseg, int M, int G)
{
    __shared__ float t[32][33];
    const int z = blockIdx.z;
    src += (size_t)z * Kseg * M;
    const int ldd = G * Kseg;
    dst += (size_t)(z / G) * M * ldd + (size_t)(z % G) * Kseg;
    const int tM = blockIdx.x * 32, tK = blockIdx.y * 32;
    const int tx = threadIdx.x & 31, ty = threadIdx.x >> 5;
#pragma unroll
    for (int r = 0; r < 4; ++r)
        t[ty + r * 8][tx] = src[(size_t)(tK + ty + r * 8) * M + tM + tx];
    __syncthreads();
#pragma unroll
    for (int r = 0; r < 4; ++r)
        dst[(size_t)(tM + ty + r * 8) * ldd + tK + tx] = (bf16)t[tx][ty + r * 8];
}

__global__ __launch_bounds__(256)
void cvt_bf_k(const float* __restrict__ src, bf16* __restrict__ dst, long n4)
{
    long i = (long)blockIdx.x * blockDim.x + threadIdx.x;
    if (i >= n4) return;
    float4 v = ((const float4*)src)[i];
    bf16x4 o; o[0] = (bf16)v.x; o[1] = (bf16)v.y; o[2] = (bf16)v.z; o[3] = (bf16)v.w;
    ((bf16x4*)dst)[i] = o;
}

// ================= CSR build (parallel scan) =================
__global__ __launch_bounds__(256)
void deg_k(const int* __restrict__ dst, int* __restrict__ deg, int E)
{
    int e = blockIdx.x * blockDim.x + threadIdx.x;
    if (e < E) atomicAdd(&deg[dst[e]], 1);
}

__global__ __launch_bounds__(256)
void blocksum_k(const int* __restrict__ deg, int* __restrict__ bsum, int N)
{
    int i = blockIdx.x * 256 + threadIdx.x;
    int v = (i < N) ? deg[i] : 0;
#pragma unroll
    for (int m = 1; m <= 32; m <<= 1) v += __shfl_xor(v, m, 64);
    __shared__ int Ls[4];
    if ((threadIdx.x & 63) == 0) Ls[threadIdx.x >> 6] = v;
    __syncthreads();
    if (threadIdx.x == 0) bsum[blockIdx.x] = Ls[0] + Ls[1] + Ls[2] + Ls[3];
}

__global__ __launch_bounds__(256)
void topscan_k(const int* __restrict__ bsum, int* __restrict__ boff, int nb)
{
    __shared__ int s[256];
    int t = threadIdx.x;
    int v = (t < nb) ? bsum[t] : 0;
    s[t] = v;
    __syncthreads();
    for (int off = 1; off < 256; off <<= 1) {
        int u = (t >= off) ? s[t - off] : 0;
        __syncthreads();
        s[t] += u;
        __syncthreads();
    }
    if (t < nb) boff[t] = s[t] - v;   // exclusive
}

__global__ __launch_bounds__(256)
void scatterscan_k(int* __restrict__ deg_wp, const int* __restrict__ boff,
                   int* __restrict__ rowptr, int N)
{
    __shared__ int s[256];
    int t = threadIdx.x;
    int i = blockIdx.x * 256 + t;
    int v = (i < N) ? deg_wp[i] : 0;
    s[t] = v;
    __syncthreads();
    for (int off = 1; off < 256; off <<= 1) {
        int u = (t >= off) ? s[t - off] : 0;
        __syncthreads();
        s[t] += u;
        __syncthreads();
    }
    if (i < N) {
        int incl = s[t] + boff[blockIdx.x];
        rowptr[i + 1] = incl;
        deg_wp[i] = incl - v;     // exclusive -> reorder write ptr
        if (i == 0) rowptr[0] = 0;
    }
}

__global__ __launch_bounds__(256)
void reorder_k(const int* __restrict__ src, const int* __restrict__ dst,
               const float* __restrict__ ew, int* __restrict__ wp,
               int* __restrict__ col, float* __restrict__ wgt, int E)
{
    int e = blockIdx.x * blockDim.x + threadIdx.x;
    if (e >= E) return;
    int d = dst[e];
    int pos = atomicAdd(&wp[d], 1);
    col[pos] = src[e];
    wgt[pos] = ew[e];
}

// ================= pull SpMM: half-wave (32 lanes x bf16x8) per node =========
// FUSE: apply per-column BN+leaky (coefs preloaded to 16 regs) to gathered
// rows before weighting — deletes the separate apply_bn pass. spmm is
// gather-latency-bound; the 3 extra VALU/elem hide under the loads.
template<bool FUSE>
__global__ __launch_bounds__(256)
void spmm_pull_k(const bf16* __restrict__ P, const int* __restrict__ rowptr,
                 const int* __restrict__ col, const float* __restrict__ wgt,
                 bf16* __restrict__ Q, int N, const float* __restrict__ coef)
{
    int node = blockIdx.x * 8 + (threadIdx.x >> 5);
    int l = threadIdx.x & 31;
    if (node >= N) return;
    float a8[8], b8[8];
    if (FUSE) {
#pragma unroll
        for (int u = 0; u < 8; ++u) {
            a8[u] = coef[l * 8 + u];
            b8[u] = coef[256 + l * 8 + u];
        }
    }
    auto tx = [&](float x, int u) {
        if (FUSE) {
            x = fmaf(x, a8[u], b8[u]);
            x = x > 0.f ? x : SLOPEV * x;
        }
        return x;
    };
    int e = rowptr[node], end = rowptr[node + 1];
    float acc[8] = {};
    for (; e + 3 < end; e += 4) {
        int   s0 = col[e],     s1 = col[e + 1], s2 = col[e + 2], s3 = col[e + 3];
        float w0 = wgt[e],     w1 = wgt[e + 1], w2 = wgt[e + 2], w3 = wgt[e + 3];
        bf16x8 v0 = *(const bf16x8*)(P + (size_t)s0 * HDIM + l * 8);
        bf16x8 v1 = *(const bf16x8*)(P + (size_t)s1 * HDIM + l * 8);
        bf16x8 v2 = *(const bf16x8*)(P + (size_t)s2 * HDIM + l * 8);
        bf16x8 v3 = *(const bf16x8*)(P + (size_t)s3 * HDIM + l * 8);
#pragma unroll
        for (int u = 0; u < 8; ++u)
            acc[u] += (tx((float)v0[u], u) * w0 + tx((float)v1[u], u) * w1)
                    + (tx((float)v2[u], u) * w2 + tx((float)v3[u], u) * w3);
    }
    for (; e + 1 < end; e += 2) {
        int   s0 = col[e], s1 = col[e + 1];
        float w0 = wgt[e], w1 = wgt[e + 1];
        bf16x8 v0 = *(const bf16x8*)(P + (size_t)s0 * HDIM + l * 8);
        bf16x8 v1 = *(const bf16x8*)(P + (size_t)s1 * HDIM + l * 8);
#pragma unroll
        for (int u = 0; u < 8; ++u)
            acc[u] += tx((float)v0[u], u) * w0 + tx((float)v1[u], u) * w1;
    }
    if (e < end) {
        int s0 = col[e]; float w0 = wgt[e];
        bf16x8 v0 = *(const bf16x8*)(P + (size_t)s0 * HDIM + l * 8);
#pragma unroll
        for (int u = 0; u < 8; ++u) acc[u] += tx((float)v0[u], u) * w0;
    }
    bf16x8 o;
#pragma unroll
    for (int u = 0; u < 8; ++u) o[u] = (bf16)acc[u];
    *(bf16x8*)(Q + (size_t)node * HDIM + l * 8) = o;
}

// ================= host =================
struct GemmArgs {
    const bf16 *A0, *A1, *A2, *A3; int nseg, segK;
    const bf16* Wt; const float* bias; const bf16* addb;
    void *o0, *o1, *o2, *o3; int ldo, M, n_store;
    float* part; int n_stats;
    const float* fuse; int fuse_nseg; int ncoef;   // frag-side BN on A
};

static void gemm(hipStream_t st, const GemmArgs& a, int GYr, bool store_bf16, bool stats)
{
    dim3 g(a.M / 128, GYr), b(256);
    if (a.fuse) {
        if (stats)
            gemm_bt_k<true, true, true><<<g, b, 0, st>>>(a.A0, a.A1, a.A2, a.A3,
                a.nseg, a.segK, a.Wt, a.bias, a.addb, a.o0, a.o1, a.o2, a.o3,
                a.ldo, a.n_store, a.part, a.n_stats, a.fuse, a.fuse_nseg, a.ncoef);
        else
            gemm_bt_k<true, false, true><<<g, b, 0, st>>>(a.A0, a.A1, a.A2, a.A3,
                a.nseg, a.segK, a.Wt, a.bias, a.addb, a.o0, a.o1, a.o2, a.o3,
                a.ldo, a.n_store, a.part, a.n_stats, a.fuse, a.fuse_nseg, a.ncoef);
    } else if (store_bf16) {
        if (stats)
            gemm_bt_k<true, true, false><<<g, b, 0, st>>>(a.A0, a.A1, a.A2, a.A3,
                a.nseg, a.segK, a.Wt, a.bias, a.addb, a.o0, a.o1, a.o2, a.o3,
                a.ldo, a.n_store, a.part, a.n_stats, nullptr, 0, 0);
        else
            gemm_bt_k<true, false, false><<<g, b, 0, st>>>(a.A0, a.A1, a.A2, a.A3,
                a.nseg, a.segK, a.Wt, a.bias, a.addb, a.o0, a.o1, a.o2, a.o3,
                a.ldo, a.n_store, a.part, a.n_stats, nullptr, 0, 0);
    } else {
        gemm_bt_k<false, false, false><<<g, b, 0, st>>>(a.A0, a.A1, a.A2, a.A3,
            a.nseg, a.segK, a.Wt, a.bias, a.addb, a.o0, a.o1, a.o2, a.o3,
            a.ldo, a.n_store, a.part, a.n_stats, nullptr, 0, 0);
    }
}

extern "C" void kernel_launch(void* const* d_in, const int* in_sizes, int n_in,
                              void* d_out, int out_size, void* d_ws, size_t ws_size,
                              hipStream_t stream)
{
    const float* x       = (const float*)d_in[0];
    const int*   ei      = (const int*)d_in[1];
    const float* ew      = (const float*)d_in[2];
    const float* W_emb   = (const float*)d_in[3];
    const float* b_emb   = (const float*)d_in[4];
    const float* conv0_W = (const float*)d_in[5];
    const float* conv0_b = (const float*)d_in[6];
    const float* norm_g  = (const float*)d_in[7];
    const float* norm_b  = (const float*)d_in[8];
    const float* conv_W  = (const float*)d_in[9];
    const float* conv_b  = (const float*)d_in[10];
    const float* mlp_W1  = (const float*)d_in[11];
    const float* mlp_b1  = (const float*)d_in[12];
    const float* mlp_g   = (const float*)d_in[13];
    const float* mlp_bb  = (const float*)d_in[14];
    const float* mlp_W2  = (const float*)d_in[15];
    const float* mlp_b2  = (const float*)d_in[16];
    const float* W_out   = (const float*)d_in[17];
    const float* b_out   = (const float*)d_in[18];

    const int N = in_sizes[0] / 128;          // 50000
    const int E = in_sizes[2];                // 800000
    const int* srcI = ei;
    const int* dstI = ei + E;
    const int N_pad = ((N + 127) / 128) * 128;
    const int GYr = N_pad / 64;               // 64-row blocks
    const int NB = (N + 255) / 256;           // scan blocks (<=256)

    const size_t NHp = (size_t)N_pad * HDIM;
    bf16* xb = (bf16*)d_ws;                      // N_pad x 128
    bf16* hb = xb + (size_t)N_pad * 128;
    bf16* cb = hb + NHp;
    bf16* p1 = cb + NHp;
    bf16* p2 = p1 + NHp;
    bf16* e1 = p2 + NHp;
    bf16* e2 = e1 + NHp;
    bf16* wa = e2 + NHp;                         // weight arena
    bf16* Wt_emb   = wa;
    bf16* Wt_conv0 = wa + 32768;
    bf16* Wt_conv  = wa + 229376;
    bf16* Wt_mlp1  = wa + 819200;
    bf16* Wt_mlp2  = wa + 1605632;
    bf16* Wt_out   = wa + 2392064;
    float* cf_h   = (float*)(wa + 2424832);      // 512 coeffs (h BN)
    float* cf_m   = cf_h + 512;                  // 2048 coeffs (mlp BN)
    float* partb  = cf_m + 2048;                 // 2*GYr*1024 floats max
    int*   rowptr = (int*)(partb + 2 * (size_t)GYr * 1024);
    int*   wp     = rowptr + (N + 1);
    int*   col    = wp + N;
    float* wgt    = (float*)(col + E);
    int*   bsum   = (int*)(wgt + E);             // 256
    int*   boff   = bsum + 256;                  // 256

    const float invn = 1.0f / (float)N;
    dim3 pg((N + 7) / 8), pb(256);

    // ---- CSR build (parallel scan) ----
    hipMemsetAsync(wp, 0, (size_t)N * 4, stream);
    deg_k<<<dim3((E + 255) / 256), dim3(256), 0, stream>>>(dstI, wp, E);
    blocksum_k<<<dim3(NB), dim3(256), 0, stream>>>(wp, bsum, N);
    topscan_k<<<dim3(1), dim3(256), 0, stream>>>(bsum, boff, NB);
    scatterscan_k<<<dim3(NB), dim3(256), 0, stream>>>(wp, boff, rowptr, N);
    reorder_k<<<dim3((E + 255) / 256), dim3(256), 0, stream>>>(srcI, dstI, ew, wp, col, wgt, E);

    // ---- convert inputs/weights ----
    cvt_bf_k<<<dim3((N * 32 + 255) / 256), dim3(256), 0, stream>>>(x, xb, (long)N * 32);
    transpose_cvt_k<<<dim3(8, 4, 1), dim3(256), 0, stream>>>(W_emb, Wt_emb, 128, 256, 1);
    transpose_cvt_k<<<dim3(8, 8, 3), dim3(256), 0, stream>>>(conv0_W, Wt_conv0, 256, 256, 3);
    transpose_cvt_k<<<dim3(8, 8, 9), dim3(256), 0, stream>>>(conv_W, Wt_conv, 256, 256, 3);
    transpose_cvt_k<<<dim3(32, 8, 3), dim3(256), 0, stream>>>(mlp_W1, Wt_mlp1, 256, 1024, 1);
    transpose_cvt_k<<<dim3(8, 32, 3), dim3(256), 0, stream>>>(mlp_W2, Wt_mlp2, 1024, 256, 1);
    transpose_cvt_k<<<dim3(4, 8, 1), dim3(256), 0, stream>>>(W_out, Wt_out, 256, 128, 1);

    // ---- embed: cb = bf16(x @ W_emb + b_emb) ----
    {
        GemmArgs a{xb, xb, xb, xb, 1, 128, Wt_emb, b_emb, nullptr,
                   cb, cb, cb, cb, HDIM, 256, N_pad, nullptr, 0, nullptr, 0, 0};
        gemm(stream, a, GYr, true, false);
    }

    // ---- conv0: hb = [cb | A.cb | A^2.cb] @ Wt_conv0 + b ; partials -> cf_h ----
    spmm_pull_k<false><<<pg, pb, 0, stream>>>(cb, rowptr, col, wgt, p1, N, nullptr);
    spmm_pull_k<false><<<pg, pb, 0, stream>>>(p1, rowptr, col, wgt, p2, N, nullptr);
    {
        GemmArgs a{cb, p1, p2, p2, 3, 256, Wt_conv0, conv0_b, nullptr,
                   hb, hb, hb, hb, HDIM, 256, N_pad, partb, N, nullptr, 0, 0};
        gemm(stream, a, GYr, true, true);
    }
    finalize_k<<<dim3(256), dim3(256), 0, stream>>>(partb, GYr, 256, norm_g, norm_b, cf_h, invn);

    for (int l = 0; l < 3; ++l) {
        // zb = leaky(bn(hb)) is FUSED: into spmm1's gather and conv's seg-0
        // A-fragments (apply_bn pass + e1 materialization eliminated)
        spmm_pull_k<true><<<pg, pb, 0, stream>>>(hb, rowptr, col, wgt, p1, N, cf_h);
        spmm_pull_k<false><<<pg, pb, 0, stream>>>(p1, rowptr, col, wgt, p2, N, nullptr);
        {
            GemmArgs a{hb, p1, p2, p2, 3, 256, Wt_conv + (size_t)l * 196608,
                       conv_b + l * 256, nullptr, cb, cb, cb, cb, HDIM, 256, N_pad,
                       nullptr, 0, cf_h, 1, 256};
            gemm(stream, a, GYr, true, false);
        }

        // W1: {p1,p2,e1,e2} = cb @ W1 + b1 (RAW hidden) ; partials -> cf_m
        {
            GemmArgs a{cb, cb, cb, cb, 1, 256, Wt_mlp1 + (size_t)l * 262144,
                       mlp_b1 + (size_t)l * 1024, nullptr, p1, p2, e1, e2, HDIM, 1024,
                       N_pad, partb, N, nullptr, 0, 0};
            gemm(stream, a, GYr, true, true);
        }
        finalize_k<<<dim3(1024), dim3(256), 0, stream>>>(partb, GYr, 1024,
                                                         mlp_g + (size_t)l * 1024,
                                                         mlp_bb + (size_t)l * 1024, cf_m, invn);

        // W2: hb += leaky(bn(hidden)) @ W2 + b2 — BN+leaky on A-fragments
        {
            GemmArgs a{p1, p2, e1, e2, 4, 256, Wt_mlp2 + (size_t)l * 262144,
                       mlp_b2 + l * 256, hb, hb, hb, hb, hb, HDIM, 256, N_pad,
                       (l < 2) ? partb : nullptr, N, cf_m, 4, 1024};
            gemm(stream, a, GYr, true, l < 2);
        }
        if (l < 2)
            finalize_k<<<dim3(256), dim3(256), 0, stream>>>(partb, GYr, 256,
                                                            norm_g + (l + 1) * 256,
                                                            norm_b + (l + 1) * 256, cf_h, invn);
    }

    // ---- out = hb @ W_out + b_out (f32) ----
    {
        GemmArgs a{hb, hb, hb, hb, 1, 256, Wt_out, b_out, nullptr,
                   d_out, d_out, d_out, d_out, 128, 128, N, nullptr, 0, nullptr, 0, 0};
        gemm(stream, a, GYr, false, false);
    }
}

// Round 8
// 1367.601 us; speedup vs baseline: 1.0100x; 1.0100x over previous
//
#include <hip/hip_runtime.h>

#define HDIM 256
#define EPSV 1e-5f
#define SLOPEV 0.01f

typedef __bf16 bf16;
typedef bf16  bf16x8 __attribute__((ext_vector_type(8)));
typedef bf16  bf16x4 __attribute__((ext_vector_type(4)));
typedef float f32x4  __attribute__((ext_vector_type(4)));

#define GLD16(g, l) __builtin_amdgcn_global_load_lds( \
    (const __attribute__((address_space(1))) void*)(g), \
    (__attribute__((address_space(3))) void*)(l), 16, 0, 0)

// ============ MFMA GEMM: 64x128 tile (short-wide), 32x64/wave ============
// out = concat_k(A0..A_{nseg-1}) * Wt^T + bias (+addb residual).
// NCOEF>0: frag-side BN+leaky on the first fuse_nseg A-segments, coef table
// (NCOEF a + NCOEF b floats) in LDS. SMEM sized per-instantiation:
// unfused 24KB (launch_bounds 6 waves/EU -> 6 blocks/CU), conv-fused
// 26.6KB, W2-fused 32KB (5 declared; HW reservation may cap at 4 - r7).
// leaky via fmaxf(f, 0.01f*f): 2 VALU instead of 3 (r8).
template<bool STORE_BF16, bool STATS, int NCOEF>
__global__ __launch_bounds__(256, NCOEF == 0 ? 6 : 5)
void gemm_bt_k(const bf16* A0, const bf16* A1, const bf16* A2, const bf16* A3,
               int nseg, int segK,
               const bf16* __restrict__ Wt,
               const float* __restrict__ bias, const bf16* __restrict__ addb,
               void* out0, void* out1, void* out2, void* out3, int ldo,
               int n_store, float* part, int n_stats,
               const float* __restrict__ fcoef, int fuse_nseg)
{
    constexpr bool FUSE_A = (NCOEF > 0);
    constexpr int SMEMSZ = 24576 + NCOEF * 8;
    __shared__ char smem[SMEMSZ];

    const int tid = threadIdx.x;
    const int wave = tid >> 6, lane = tid & 63;
    const int quad = lane >> 4, l16 = lane & 15;
    const int waveM = (wave >> 1) * 32, waveN = (wave & 1) * 64;

    // T1: XCD-aware swizzle (guarded on nwg % 8 == 0).
    int bid = blockIdx.y * gridDim.x + blockIdx.x;
    const int nwg = gridDim.x * gridDim.y;
    if ((nwg & 7) == 0) {
        const int cpx = nwg >> 3;
        bid = (bid & 7) * cpx + (bid >> 3);
    }
    const int bx = bid % gridDim.x, by = bid / gridDim.x;
    const int bm = by * 64, bn = bx * 128;
    const int K = nseg * segK;

    const bf16* segs[4] = {A0, A1, A2, A3};
    const int srow = tid >> 2;            // 0..63
    const int skof = (tid & 3) * 8;       // 0,8,16,24 (bf16 elems)

    f32x4 acc[2][4] = {};

    const int T = K >> 5;                 // K-steps of 32

    auto stageA = [&](int s, int kt, int b) {
        const bf16* gA = segs[s] + (size_t)(bm + srow) * segK + kt + skof;
        GLD16(gA, smem + b * 4096 + wave * 1024);
    };
    auto stageB = [&](int s, int kt, int b) {
        const bf16* gB = Wt + (size_t)(bn + srow) * K + s * segK + kt + skof;
        char* lB = smem + 8192 + b * 8192 + wave * 1024;
        GLD16(gB,                  lB);
        GLD16(gB + (size_t)64 * K, lB + 4096);
    };

    // prologue: coef table -> LDS (FUSE only), stage step 0
    if (FUSE_A) {
        float* aT = (float*)(smem + 24576);
        float* bT = aT + NCOEF;
        for (int i = tid; i < NCOEF; i += 256) {
            aT[i] = fcoef[i];
            bT[i] = fcoef[NCOEF + i];
        }
    }
    stageA(0, 0, 0);
    stageB(0, 0, 0);
    __syncthreads();

    int s = 0, kt = 0;
    for (int t = 0; t < T; ++t) {
        int s2 = s, kt2 = kt + 32;
        if (kt2 == segK) { s2++; kt2 = 0; }
        if (t + 1 < T) {                   // issue-early prefetch
            stageA(s2, kt2, (t + 1) & 1);
            stageB(s2, kt2, (t + 1) & 1);
        }

        const bf16* pa = (const bf16*)(smem + (t & 1) * 4096)
                         + (waveM + l16) * 32 + quad * 8;
        const bf16* pb = (const bf16*)(smem + 8192 + (t & 1) * 8192)
                         + (waveN + l16) * 32 + quad * 8;
        bf16x8 a0 = *(const bf16x8*)(pa);
        bf16x8 a1 = *(const bf16x8*)(pa + 16 * 32);
        bf16x8 b0 = *(const bf16x8*)(pb);
        bf16x8 b1 = *(const bf16x8*)(pb + 16 * 32);
        bf16x8 b2 = *(const bf16x8*)(pb + 32 * 32);
        bf16x8 b3 = *(const bf16x8*)(pb + 48 * 32);

        if (FUSE_A && s < fuse_nseg) {
            // per-K-column affine + leaky on A-fragments (coefs broadcast
            // across the 16 l16 lanes -> conflict-free LDS reads)
            const float* aT = (const float*)(smem + 24576);
            const float* bT = aT + NCOEF;
            int kb = s * segK + kt + quad * 8;
            float av[8], dv[8];
            *(float4*)(av)     = *(const float4*)(aT + kb);
            *(float4*)(av + 4) = *(const float4*)(aT + kb + 4);
            *(float4*)(dv)     = *(const float4*)(bT + kb);
            *(float4*)(dv + 4) = *(const float4*)(bT + kb + 4);
#pragma unroll
            for (int u = 0; u < 8; ++u) {
                float f0 = fmaf((float)a0[u], av[u], dv[u]);
                a0[u] = (bf16)fmaxf(f0, SLOPEV * f0);
                float f1 = fmaf((float)a1[u], av[u], dv[u]);
                a1[u] = (bf16)fmaxf(f1, SLOPEV * f1);
            }
        }

        acc[0][0] = __builtin_amdgcn_mfma_f32_16x16x32_bf16(a0, b0, acc[0][0], 0, 0, 0);
        acc[0][1] = __builtin_amdgcn_mfma_f32_16x16x32_bf16(a0, b1, acc[0][1], 0, 0, 0);
        acc[0][2] = __builtin_amdgcn_mfma_f32_16x16x32_bf16(a0, b2, acc[0][2], 0, 0, 0);
        acc[0][3] = __builtin_amdgcn_mfma_f32_16x16x32_bf16(a0, b3, acc[0][3], 0, 0, 0);
        acc[1][0] = __builtin_amdgcn_mfma_f32_16x16x32_bf16(a1, b0, acc[1][0], 0, 0, 0);
        acc[1][1] = __builtin_amdgcn_mfma_f32_16x16x32_bf16(a1, b1, acc[1][1], 0, 0, 0);
        acc[1][2] = __builtin_amdgcn_mfma_f32_16x16x32_bf16(a1, b2, acc[1][2], 0, 0, 0);
        acc[1][3] = __builtin_amdgcn_mfma_f32_16x16x32_bf16(a1, b3, acc[1][3], 0, 0, 0);

        __syncthreads();
        s = s2; kt = kt2;
    }

    float bv[4];
#pragma unroll
    for (int j = 0; j < 4; ++j)
        bv[j] = bias ? bias[bn + waveN + j * 16 + l16] : 0.f;
#pragma unroll
    for (int i = 0; i < 2; ++i)
#pragma unroll
        for (int j = 0; j < 4; ++j)
#pragma unroll
            for (int r = 0; r < 4; ++r)
                acc[i][j][r] += bv[j];

    void* outs[4] = {out0, out1, out2, out3};

    if (STORE_BF16) {
        // wave-private 32x64 staging tile, row stride 72 bf16 (144B, 16B-mult)
        char* stg = smem + wave * 4608;
        float s8[8] = {}, q8[8] = {};
        const int rsel = lane >> 3, csel = lane & 7;
#pragma unroll
        for (int i = 0; i < 2; ++i)
#pragma unroll
            for (int j = 0; j < 4; ++j)
#pragma unroll
                for (int r = 0; r < 4; ++r)
                    *(bf16*)(stg + ((i * 16 + quad * 4 + r) * 72 + j * 16 + l16) * 2)
                        = (bf16)acc[i][j][r];
        // same-wave DS ops are in-order: reads below see writes above
#pragma unroll
        for (int rr = 0; rr < 4; ++rr) {
            int rl = rsel + rr * 8;
            bf16x8 v = *(const bf16x8*)(stg + (rl * 72 + csel * 8) * 2);
            int rowg = bm + waveM + rl;
            int colg = bn + waveN + csel * 8;
            int cseg = colg >> 8, cloc = colg & 255;
            size_t idx = (size_t)rowg * ldo + cloc;
            float f[8];
#pragma unroll
            for (int u = 0; u < 8; ++u) f[u] = (float)v[u];
            if (addb) {
                bf16x8 o = *(const bf16x8*)(addb + idx);
#pragma unroll
                for (int u = 0; u < 8; ++u) f[u] += (float)o[u];
            }
            bf16x8 w;
#pragma unroll
            for (int u = 0; u < 8; ++u) w[u] = (bf16)f[u];
            if (rowg < n_store) *(bf16x8*)((bf16*)outs[cseg] + idx) = w;
            if (STATS && rowg < n_stats) {
#pragma unroll
                for (int u = 0; u < 8; ++u) { s8[u] += f[u]; q8[u] += f[u] * f[u]; }
            }
        }
        if (STATS) {
            // reduce across rsel (lane bits 3..5)
#pragma unroll
            for (int m = 8; m <= 32; m <<= 1)
#pragma unroll
                for (int u = 0; u < 8; ++u) {
                    s8[u] += __shfl_xor(s8[u], m, 64);
                    q8[u] += __shfl_xor(q8[u], m, 64);
                }
            float* Ls = (float*)(smem + 18432);   // [4][64]
            float* Lq = Ls + 256;                 // [4][64]
            if (rsel == 0) {
#pragma unroll
                for (int u = 0; u < 8; ++u) {
                    Ls[wave * 64 + csel * 8 + u] = s8[u];
                    Lq[wave * 64 + csel * 8 + u] = q8[u];
                }
            }
            __syncthreads();
            if (tid < 128) {
                // cols 0..63: waves 0,2 ; cols 64..127: waves 1,3
                int hi = tid >> 6, c6 = tid & 63;
                float sv = Ls[hi * 64 + c6] + Ls[(hi + 2) * 64 + c6];
                float qv = Lq[hi * 64 + c6] + Lq[(hi + 2) * 64 + c6];
                int Mtot = gridDim.x * 128;
                int colg = bn + tid;
                part[(size_t)by * Mtot + colg] = sv;
                part[(size_t)(gridDim.y + by) * Mtot + colg] = qv;
            }
        }
    } else {
#pragma unroll
        for (int i = 0; i < 2; ++i)
#pragma unroll
            for (int j = 0; j < 4; ++j) {
                int colg = bn + waveN + j * 16 + l16;
                int cseg = colg >> 8, cloc = colg & 255;
#pragma unroll
                for (int r = 0; r < 4; ++r) {
                    int rowg = bm + waveM + i * 16 + quad * 4 + r;
                    if (rowg < n_store)
                        ((float*)outs[cseg])[(size_t)rowg * ldo + cloc] = acc[i][j][r];
                }
            }
    }
}

// ================= finalize: one block per column, tree reduce =================
__global__ __launch_bounds__(256)
void finalize_k(const float* __restrict__ part, int GY, int M,
                const float* __restrict__ g, const float* __restrict__ bb,
                float* __restrict__ coef, float invn)
{
    const int c = blockIdx.x;
    const int t = threadIdx.x;
    float s = 0.f, q = 0.f;
    const float* ps = part + c;
    const float* pq = part + (size_t)GY * M + c;
    for (int i = t; i < GY; i += 256) {
        s += ps[(size_t)i * M];
        q += pq[(size_t)i * M];
    }
#pragma unroll
    for (int m = 1; m <= 32; m <<= 1) {
        s += __shfl_xor(s, m, 64);
        q += __shfl_xor(q, m, 64);
    }
    __shared__ float Ls[4], Lq[4];
    const int w = t >> 6, l = t & 63;
    if (l == 0) { Ls[w] = s; Lq[w] = q; }
    __syncthreads();
    if (t == 0) {
        s = Ls[0] + Ls[1] + Ls[2] + Ls[3];
        q = Lq[0] + Lq[1] + Lq[2] + Lq[3];
        float mean = s * invn;
        float var  = q * invn - mean * mean;
        float a = g[c] * rsqrtf(var + EPSV);
        coef[c]     = a;
        coef[M + c] = bb[c] - mean * a;
    }
}

// ================= transpose+convert =================
__global__ __launch_bounds__(256)
void transpose_cvt_k(const float* __restrict__ src, bf16* __restrict__ dst,
                     int Kseg, int M, int G)
{
    __shared__ float t[32][33];
    const int z = blockIdx.z;
    src += (size_t)z * Kseg * M;
    const int ldd = G * Kseg;
    dst += (size_t)(z / G) * M * ldd + (size_t)(z % G) * Kseg;
    const int tM = blockIdx.x * 32, tK = blockIdx.y * 32;
    const int tx = threadIdx.x & 31, ty = threadIdx.x >> 5;
#pragma unroll
    for (int r = 0; r < 4; ++r)
        t[ty + r * 8][tx] = src[(size_t)(tK + ty + r * 8) * M + tM + tx];
    __syncthreads();
#pragma unroll
    for (int r = 0; r < 4; ++r)
        dst[(size_t)(tM + ty + r * 8) * ldd + tK + tx] = (bf16)t[tx][ty + r * 8];
}

__global__ __launch_bounds__(256)
void cvt_bf_k(const float* __restrict__ src, bf16* __restrict__ dst, long n4)
{
    long i = (long)blockIdx.x * blockDim.x + threadIdx.x;
    if (i >= n4) return;
    float4 v = ((const float4*)src)[i];
    bf16x4 o; o[0] = (bf16)v.x; o[1] = (bf16)v.y; o[2] = (bf16)v.z; o[3] = (bf16)v.w;
    ((bf16x4*)dst)[i] = o;
}

// ================= CSR build (parallel scan) =================
__global__ __launch_bounds__(256)
void deg_k(const int* __restrict__ dst, int* __restrict__ deg, int E)
{
    int e = blockIdx.x * blockDim.x + threadIdx.x;
    if (e < E) atomicAdd(&deg[dst[e]], 1);
}

__global__ __launch_bounds__(256)
void blocksum_k(const int* __restrict__ deg, int* __restrict__ bsum, int N)
{
    int i = blockIdx.x * 256 + threadIdx.x;
    int v = (i < N) ? deg[i] : 0;
#pragma unroll
    for (int m = 1; m <= 32; m <<= 1) v += __shfl_xor(v, m, 64);
    __shared__ int Ls[4];
    if ((threadIdx.x & 63) == 0) Ls[threadIdx.x >> 6] = v;
    __syncthreads();
    if (threadIdx.x == 0) bsum[blockIdx.x] = Ls[0] + Ls[1] + Ls[2] + Ls[3];
}

__global__ __launch_bounds__(256)
void topscan_k(const int* __restrict__ bsum, int* __restrict__ boff, int nb)
{
    __shared__ int s[256];
    int t = threadIdx.x;
    int v = (t < nb) ? bsum[t] : 0;
    s[t] = v;
    __syncthreads();
    for (int off = 1; off < 256; off <<= 1) {
        int u = (t >= off) ? s[t - off] : 0;
        __syncthreads();
        s[t] += u;
        __syncthreads();
    }
    if (t < nb) boff[t] = s[t] - v;   // exclusive
}

__global__ __launch_bounds__(256)
void scatterscan_k(int* __restrict__ deg_wp, const int* __restrict__ boff,
                   int* __restrict__ rowptr, int N)
{
    __shared__ int s[256];
    int t = threadIdx.x;
    int i = blockIdx.x * 256 + t;
    int v = (i < N) ? deg_wp[i] : 0;
    s[t] = v;
    __syncthreads();
    for (int off = 1; off < 256; off <<= 1) {
        int u = (t >= off) ? s[t - off] : 0;
        __syncthreads();
        s[t] += u;
        __syncthreads();
    }
    if (i < N) {
        int incl = s[t] + boff[blockIdx.x];
        rowptr[i + 1] = incl;
        deg_wp[i] = incl - v;     // exclusive -> reorder write ptr
        if (i == 0) rowptr[0] = 0;
    }
}

__global__ __launch_bounds__(256)
void reorder_k(const int* __restrict__ src, const int* __restrict__ dst,
               const float* __restrict__ ew, int* __restrict__ wp,
               int* __restrict__ col, float* __restrict__ wgt, int E)
{
    int e = blockIdx.x * blockDim.x + threadIdx.x;
    if (e >= E) return;
    int d = dst[e];
    int pos = atomicAdd(&wp[d], 1);
    col[pos] = src[e];
    wgt[pos] = ew[e];
}

// ================= pull SpMM: half-wave (32 lanes x bf16x8) per node =========
// 8-edge unroll (r8): 8 gather loads in flight per half-wave for the
// L2/L3-latency-bound random row gathers (avg degree 16 -> 2 main iters).
// FUSE: per-column BN+leaky (coefs in 16 regs) applied to gathered rows.
template<bool FUSE>
__global__ __launch_bounds__(256)
void spmm_pull_k(const bf16* __restrict__ P, const int* __restrict__ rowptr,
                 const int* __restrict__ col, const float* __restrict__ wgt,
                 bf16* __restrict__ Q, int N, const float* __restrict__ coef)
{
    int node = blockIdx.x * 8 + (threadIdx.x >> 5);
    int l = threadIdx.x & 31;
    if (node >= N) return;
    float a8[8], b8[8];
    if (FUSE) {
#pragma unroll
        for (int u = 0; u < 8; ++u) {
            a8[u] = coef[l * 8 + u];
            b8[u] = coef[256 + l * 8 + u];
        }
    }
    auto tx = [&](float x, int u) {
        if (FUSE) {
            x = fmaf(x, a8[u], b8[u]);
            x = fmaxf(x, SLOPEV * x);
        }
        return x;
    };
    int e = rowptr[node], end = rowptr[node + 1];
    float acc[8] = {};
    for (; e + 7 < end; e += 8) {
        int   sx[8]; float wx[8];
#pragma unroll
        for (int k = 0; k < 8; ++k) { sx[k] = col[e + k]; wx[k] = wgt[e + k]; }
        bf16x8 v[8];
#pragma unroll
        for (int k = 0; k < 8; ++k)
            v[k] = *(const bf16x8*)(P + (size_t)sx[k] * HDIM + l * 8);
#pragma unroll
        for (int k = 0; k < 8; ++k)
#pragma unroll
            for (int u = 0; u < 8; ++u)
                acc[u] += tx((float)v[k][u], u) * wx[k];
    }
    for (; e + 3 < end; e += 4) {
        int   s0 = col[e],     s1 = col[e + 1], s2 = col[e + 2], s3 = col[e + 3];
        float w0 = wgt[e],     w1 = wgt[e + 1], w2 = wgt[e + 2], w3 = wgt[e + 3];
        bf16x8 v0 = *(const bf16x8*)(P + (size_t)s0 * HDIM + l * 8);
        bf16x8 v1 = *(const bf16x8*)(P + (size_t)s1 * HDIM + l * 8);
        bf16x8 v2 = *(const bf16x8*)(P + (size_t)s2 * HDIM + l * 8);
        bf16x8 v3 = *(const bf16x8*)(P + (size_t)s3 * HDIM + l * 8);
#pragma unroll
        for (int u = 0; u < 8; ++u)
            acc[u] += (tx((float)v0[u], u) * w0 + tx((float)v1[u], u) * w1)
                    + (tx((float)v2[u], u) * w2 + tx((float)v3[u], u) * w3);
    }
    for (; e + 1 < end; e += 2) {
        int   s0 = col[e], s1 = col[e + 1];
        float w0 = wgt[e], w1 = wgt[e + 1];
        bf16x8 v0 = *(const bf16x8*)(P + (size_t)s0 * HDIM + l * 8);
        bf16x8 v1 = *(const bf16x8*)(P + (size_t)s1 * HDIM + l * 8);
#pragma unroll
        for (int u = 0; u < 8; ++u)
            acc[u] += tx((float)v0[u], u) * w0 + tx((float)v1[u], u) * w1;
    }
    if (e < end) {
        int s0 = col[e]; float w0 = wgt[e];
        bf16x8 v0 = *(const bf16x8*)(P + (size_t)s0 * HDIM + l * 8);
#pragma unroll
        for (int u = 0; u < 8; ++u) acc[u] += tx((float)v0[u], u) * w0;
    }
    bf16x8 o;
#pragma unroll
    for (int u = 0; u < 8; ++u) o[u] = (bf16)acc[u];
    *(bf16x8*)(Q + (size_t)node * HDIM + l * 8) = o;
}

// ================= host =================
struct GemmArgs {
    const bf16 *A0, *A1, *A2, *A3; int nseg, segK;
    const bf16* Wt; const float* bias; const bf16* addb;
    void *o0, *o1, *o2, *o3; int ldo, M, n_store;
    float* part; int n_stats;
    const float* fuse; int fuse_nseg; int ncoef;   // frag-side BN on A
};

static void gemm(hipStream_t st, const GemmArgs& a, int GYr, bool store_bf16, bool stats)
{
    dim3 g(a.M / 128, GYr), b(256);
    if (a.fuse && a.ncoef == 1024) {
        if (stats)
            gemm_bt_k<true, true, 1024><<<g, b, 0, st>>>(a.A0, a.A1, a.A2, a.A3,
                a.nseg, a.segK, a.Wt, a.bias, a.addb, a.o0, a.o1, a.o2, a.o3,
                a.ldo, a.n_store, a.part, a.n_stats, a.fuse, a.fuse_nseg);
        else
            gemm_bt_k<true, false, 1024><<<g, b, 0, st>>>(a.A0, a.A1, a.A2, a.A3,
                a.nseg, a.segK, a.Wt, a.bias, a.addb, a.o0, a.o1, a.o2, a.o3,
                a.ldo, a.n_store, a.part, a.n_stats, a.fuse, a.fuse_nseg);
    } else if (a.fuse) {
        gemm_bt_k<true, false, 256><<<g, b, 0, st>>>(a.A0, a.A1, a.A2, a.A3,
            a.nseg, a.segK, a.Wt, a.bias, a.addb, a.o0, a.o1, a.o2, a.o3,
            a.ldo, a.n_store, a.part, a.n_stats, a.fuse, a.fuse_nseg);
    } else if (store_bf16) {
        if (stats)
            gemm_bt_k<true, true, 0><<<g, b, 0, st>>>(a.A0, a.A1, a.A2, a.A3,
                a.nseg, a.segK, a.Wt, a.bias, a.addb, a.o0, a.o1, a.o2, a.o3,
                a.ldo, a.n_store, a.part, a.n_stats, nullptr, 0);
        else
            gemm_bt_k<true, false, 0><<<g, b, 0, st>>>(a.A0, a.A1, a.A2, a.A3,
                a.nseg, a.segK, a.Wt, a.bias, a.addb, a.o0, a.o1, a.o2, a.o3,
                a.ldo, a.n_store, a.part, a.n_stats, nullptr, 0);
    } else {
        gemm_bt_k<false, false, 0><<<g, b, 0, st>>>(a.A0, a.A1, a.A2, a.A3,
            a.nseg, a.segK, a.Wt, a.bias, a.addb, a.o0, a.o1, a.o2, a.o3,
            a.ldo, a.n_store, a.part, a.n_stats, nullptr, 0);
    }
}

extern "C" void kernel_launch(void* const* d_in, const int* in_sizes, int n_in,
                              void* d_out, int out_size, void* d_ws, size_t ws_size,
                              hipStream_t stream)
{
    const float* x       = (const float*)d_in[0];
    const int*   ei      = (const int*)d_in[1];
    const float* ew      = (const float*)d_in[2];
    const float* W_emb   = (const float*)d_in[3];
    const float* b_emb   = (const float*)d_in[4];
    const float* conv0_W = (const float*)d_in[5];
    const float* conv0_b = (const float*)d_in[6];
    const float* norm_g  = (const float*)d_in[7];
    const float* norm_b  = (const float*)d_in[8];
    const float* conv_W  = (const float*)d_in[9];
    const float* conv_b  = (const float*)d_in[10];
    const float* mlp_W1  = (const float*)d_in[11];
    const float* mlp_b1  = (const float*)d_in[12];
    const float* mlp_g   = (const float*)d_in[13];
    const float* mlp_bb  = (const float*)d_in[14];
    const float* mlp_W2  = (const float*)d_in[15];
    const float* mlp_b2  = (const float*)d_in[16];
    const float* W_out   = (const float*)d_in[17];
    const float* b_out   = (const float*)d_in[18];

    const int N = in_sizes[0] / 128;          // 50000
    const int E = in_sizes[2];                // 800000
    const int* srcI = ei;
    const int* dstI = ei + E;
    const int N_pad = ((N + 127) / 128) * 128;
    const int GYr = N_pad / 64;               // 64-row blocks
    const int NB = (N + 255) / 256;           // scan blocks (<=256)

    const size_t NHp = (size_t)N_pad * HDIM;
    bf16* xb = (bf16*)d_ws;                      // N_pad x 128
    bf16* hb = xb + (size_t)N_pad * 128;
    bf16* cb = hb + NHp;
    bf16* p1 = cb + NHp;
    bf16* p2 = p1 + NHp;
    bf16* e1 = p2 + NHp;
    bf16* e2 = e1 + NHp;
    bf16* wa = e2 + NHp;                         // weight arena
    bf16* Wt_emb   = wa;
    bf16* Wt_conv0 = wa + 32768;
    bf16* Wt_conv  = wa + 229376;
    bf16* Wt_mlp1  = wa + 819200;
    bf16* Wt_mlp2  = wa + 1605632;
    bf16* Wt_out   = wa + 2392064;
    float* cf_h   = (float*)(wa + 2424832);      // 512 coeffs (h BN)
    float* cf_m   = cf_h + 512;                  // 2048 coeffs (mlp BN)
    float* partb  = cf_m + 2048;                 // 2*GYr*1024 floats max
    int*   rowptr = (int*)(partb + 2 * (size_t)GYr * 1024);
    int*   wp     = rowptr + (N + 1);
    int*   col    = wp + N;
    float* wgt    = (float*)(col + E);
    int*   bsum   = (int*)(wgt + E);             // 256
    int*   boff   = bsum + 256;                  // 256

    const float invn = 1.0f / (float)N;
    dim3 pg((N + 7) / 8), pb(256);

    // ---- CSR build (parallel scan) ----
    hipMemsetAsync(wp, 0, (size_t)N * 4, stream);
    deg_k<<<dim3((E + 255) / 256), dim3(256), 0, stream>>>(dstI, wp, E);
    blocksum_k<<<dim3(NB), dim3(256), 0, stream>>>(wp, bsum, N);
    topscan_k<<<dim3(1), dim3(256), 0, stream>>>(bsum, boff, NB);
    scatterscan_k<<<dim3(NB), dim3(256), 0, stream>>>(wp, boff, rowptr, N);
    reorder_k<<<dim3((E + 255) / 256), dim3(256), 0, stream>>>(srcI, dstI, ew, wp, col, wgt, E);

    // ---- convert inputs/weights ----
    cvt_bf_k<<<dim3((N * 32 + 255) / 256), dim3(256), 0, stream>>>(x, xb, (long)N * 32);
    transpose_cvt_k<<<dim3(8, 4, 1), dim3(256), 0, stream>>>(W_emb, Wt_emb, 128, 256, 1);
    transpose_cvt_k<<<dim3(8, 8, 3), dim3(256), 0, stream>>>(conv0_W, Wt_conv0, 256, 256, 3);
    transpose_cvt_k<<<dim3(8, 8, 9), dim3(256), 0, stream>>>(conv_W, Wt_conv, 256, 256, 3);
    transpose_cvt_k<<<dim3(32, 8, 3), dim3(256), 0, stream>>>(mlp_W1, Wt_mlp1, 256, 1024, 1);
    transpose_cvt_k<<<dim3(8, 32, 3), dim3(256), 0, stream>>>(mlp_W2, Wt_mlp2, 1024, 256, 1);
    transpose_cvt_k<<<dim3(4, 8, 1), dim3(256), 0, stream>>>(W_out, Wt_out, 256, 128, 1);

    // ---- embed: cb = bf16(x @ W_emb + b_emb) ----
    {
        GemmArgs a{xb, xb, xb, xb, 1, 128, Wt_emb, b_emb, nullptr,
                   cb, cb, cb, cb, HDIM, 256, N_pad, nullptr, 0, nullptr, 0, 0};
        gemm(stream, a, GYr, true, false);
    }

    // ---- conv0: hb = [cb | A.cb | A^2.cb] @ Wt_conv0 + b ; partials -> cf_h ----
    spmm_pull_k<false><<<pg, pb, 0, stream>>>(cb, rowptr, col, wgt, p1, N, nullptr);
    spmm_pull_k<false><<<pg, pb, 0, stream>>>(p1, rowptr, col, wgt, p2, N, nullptr);
    {
        GemmArgs a{cb, p1, p2, p2, 3, 256, Wt_conv0, conv0_b, nullptr,
                   hb, hb, hb, hb, HDIM, 256, N_pad, partb, N, nullptr, 0, 0};
        gemm(stream, a, GYr, true, true);
    }
    finalize_k<<<dim3(256), dim3(256), 0, stream>>>(partb, GYr, 256, norm_g, norm_b, cf_h, invn);

    for (int l = 0; l < 3; ++l) {
        // zb = leaky(bn(hb)) is FUSED: into spmm1's gather and conv's seg-0
        // A-fragments (apply_bn pass + e1 materialization eliminated)
        spmm_pull_k<true><<<pg, pb, 0, stream>>>(hb, rowptr, col, wgt, p1, N, cf_h);
        spmm_pull_k<false><<<pg, pb, 0, stream>>>(p1, rowptr, col, wgt, p2, N, nullptr);
        {
            GemmArgs a{hb, p1, p2, p2, 3, 256, Wt_conv + (size_t)l * 196608,
                       conv_b + l * 256, nullptr, cb, cb, cb, cb, HDIM, 256, N_pad,
                       nullptr, 0, cf_h, 1, 256};
            gemm(stream, a, GYr, true, false);
        }

        // W1: {p1,p2,e1,e2} = cb @ W1 + b1 (RAW hidden) ; partials -> cf_m
        {
            GemmArgs a{cb, cb, cb, cb, 1, 256, Wt_mlp1 + (size_t)l * 262144,
                       mlp_b1 + (size_t)l * 1024, nullptr, p1, p2, e1, e2, HDIM, 1024,
                       N_pad, partb, N, nullptr, 0, 0};
            gemm(stream, a, GYr, true, true);
        }
        finalize_k<<<dim3(1024), dim3(256), 0, stream>>>(partb, GYr, 1024,
                                                         mlp_g + (size_t)l * 1024,
                                                         mlp_bb + (size_t)l * 1024, cf_m, invn);

        // W2: hb += leaky(bn(hidden)) @ W2 + b2 — BN+leaky on A-fragments
        {
            GemmArgs a{p1, p2, e1, e2, 4, 256, Wt_mlp2 + (size_t)l * 262144,
                       mlp_b2 + l * 256, hb, hb, hb, hb, hb, HDIM, 256, N_pad,
                       (l < 2) ? partb : nullptr, N, cf_m, 4, 1024};
            gemm(stream, a, GYr, true, l < 2);
        }
        if (l < 2)
            finalize_k<<<dim3(256), dim3(256), 0, stream>>>(partb, GYr, 256,
                                                            norm_g + (l + 1) * 256,
                                                            norm_b + (l + 1) * 256, cf_h, invn);
    }

    // ---- out = hb @ W_out + b_out (f32) ----
    {
        GemmArgs a{hb, hb, hb, hb, 1, 256, Wt_out, b_out, nullptr,
                   d_out, d_out, d_out, d_out, 128, 128, N, nullptr, 0, nullptr, 0, 0};
        gemm(stream, a, GYr, false, false);
    }
}